// Round 12
// baseline (85.431 us; speedup 1.0000x reference)
//
#include <hip/hip_runtime.h>
#include <math.h>

#define NQ 10
#define RPB 8   // rows per block, 512 blocks

// ---------------------------------------------------------------------------
// Compile-time term table. Slot u = s*256 + lane. Variable slots per wave:
//   wave0 (lanes 0-63): 8   wave1: 3   wave2: 3   wave3: 4
// Lane groups (pow2-aligned for shfl_xor segment reduce):
//   0-31:q8  32-63:q9  64-95:q0  96-127:q1  128-159:q6  160-191:q7
//   192-199:q4  200-207:q5  208-215:q2  216-223:q3  224-255: invalid
// post: packed POST-ring1-conj site codes (x|z<<1), bits 0-19.
// pre : packed PRE-conj codes (bits 0-19) | sign<<20 | valid<<21.
// Term = sign * [prod a(i,pre_i)] * [prod E(i,post_i)], quad-factored:
// idx0 = w&255 (sites0-3), idx1 = (w>>8)&255 (sites4-7), idxp = (w>>16)&15.
// ---------------------------------------------------------------------------
struct TP { unsigned post, pre; };
struct TermsTab { TP t[2048]; };

constexpr TermsTab build_terms() {
    TermsTab T{};
    for (int u = 0; u < 2048; ++u) {
        const int lane = u & 255, s = u >> 8;
        const int wvv = lane >> 6;
        const int nsl = (wvv == 0) ? 8 : ((wvv == 3) ? 4 : 3);
        int q = -1, g0 = 0;
        if      (lane < 32)  { q = 8; g0 = 0;   }
        else if (lane < 64)  { q = 9; g0 = 32;  }
        else if (lane < 96)  { q = 0; g0 = 64;  }
        else if (lane < 128) { q = 1; g0 = 96;  }
        else if (lane < 160) { q = 6; g0 = 128; }
        else if (lane < 192) { q = 7; g0 = 160; }
        else if (lane < 200) { q = 4; g0 = 192; }
        else if (lane < 208) { q = 5; g0 = 200; }
        else if (lane < 216) { q = 2; g0 = 208; }
        else if (lane < 224) { q = 3; g0 = 216; }
        T.t[u].post = 0u; T.t[u].pre = 0u;
        if (q < 0 || s >= nsl) continue;
        const int tau = (lane - g0) * nsl + s;

        int m = 1 << q;                               // ring-2 Z-string
        for (int ii = 9; ii >= 0; --ii) {
            int tt = (ii + 2) % 10;
            if ((m >> tt) & 1) m ^= 1 << ii;
        }
        int Lp = 0;
        for (int i = 0; i < 10; ++i) Lp += (m >> i) & 1;
        int cnt = 1;
        for (int k = 0; k < Lp; ++k) cnt *= 3;
        if (tau >= cnt) continue;

        int rem = tau;                                // digits: 0->X,1->Y,2->Z
        unsigned xm = 0, zm = 0;
        for (int i = 0; i < 10; ++i) {
            if ((m >> i) & 1) {
                int d = rem % 3; rem /= 3;
                if (d == 0)      { xm |= 1u << i; }
                else if (d == 1) { xm |= 1u << i; zm |= 1u << i; }
                else             { zm |= 1u << i; }
            }
        }
        unsigned wpre = 0;
        for (int i = 0; i < 10; ++i)
            wpre |= (((xm >> i) & 1u) | (((zm >> i) & 1u) << 1)) << (2 * i);

        unsigned sgn = 0;                             // ring-1 conj (i=9 first)
        for (int i = 9; i >= 0; --i) {
            int c = i, tt = (i + 1) % 10;
            unsigned xc = (xm >> c) & 1u, zt = (zm >> tt) & 1u;
            unsigned xt = (xm >> tt) & 1u, zc = (zm >> c) & 1u;
            sgn ^= xc & zt & (xt ^ zc ^ 1u);
            xm ^= xc << tt;
            zm ^= zt << c;
        }
        unsigned wpost = 0;
        for (int i = 0; i < 10; ++i)
            wpost |= (((xm >> i) & 1u) | (((zm >> i) & 1u) << 1)) << (2 * i);

        T.t[u].post = wpost;
        T.t[u].pre  = wpre | (sgn << 20) | (1u << 21);
    }
    return T;
}

__device__ constexpr TermsTab TERMS = build_terms();

__device__ __forceinline__ float fast_tanh(float v) {
    float e = __expf(2.f * v);
    return 1.f - 2.f / (e + 1.f);
}

// ---------------------------------------------------------------------------
// Mega kernel: 8 rows/block, 256 threads, 512 blocks.
// ---------------------------------------------------------------------------
__global__ __launch_bounds__(256) void qse_mega(
    const float* __restrict__ x,     // (4096,512)
    const float* __restrict__ W_in,  // (512,10)
    const float* __restrict__ b_in,  // (10)
    const float* __restrict__ qw,    // (2,10,3)
    const float* __restrict__ W1,    // (10,64)
    const float* __restrict__ b1,    // (64)
    const float* __restrict__ W2,    // (64,256)
    const float* __restrict__ b2,    // (256)
    float* __restrict__ out)         // (4096,256)
{
    __shared__ float Wt[NQ][512];        // transposed W_in (20 KB)
    __shared__ float Rsh[NQ][8];
    __shared__ float absh[NQ][3];
    __shared__ float angsh[RPB][NQ];
    __shared__ float E2tmp[RPB][5][16];
    __shared__ float E4d[RPB][2][256];   // 16 KB
    __shared__ float E2P[RPB][32];
    __shared__ float A2tmp[5][16];
    __shared__ float A4d[2][256];
    __shared__ float A2P[32];
    __shared__ float zsh[RPB][NQ];
    __shared__ float hsh[RPB][64];

    const int t = threadIdx.x;
    const int lane = t & 63;
    const int wv = t >> 6;
    const int row0 = blockIdx.x * RPB;
    const int nsl = (wv == 0) ? 8 : ((wv == 3) ? 4 : 3);

    // ---- issue x loads for this wave's two rows (wv, wv+4) ----
    const float* xr0 = x + (size_t)(row0 + wv) * 512;
    const float* xr1 = x + (size_t)(row0 + wv + 4) * 512;
    float xv0[8], xv1[8];
    #pragma unroll
    for (int k = 0; k < 8; ++k) xv0[k] = xr0[lane + 64 * k];
    #pragma unroll
    for (int k = 0; k < 8; ++k) xv1[k] = xr1[lane + 64 * k];

    // ---- prefetch term codes (constexpr table) ----
    TP tp[8];
    #pragma unroll
    for (int s = 0; s < 8; ++s)
        tp[s] = (s < nsl) ? TERMS.t[s * 256 + t] : TP{0u, 0u};

    // ---- stage W_in transposed into LDS (coalesced float4 reads) ----
    #pragma unroll
    for (int i = 0; i < 5; ++i) {
        const int e4 = t + 256 * i;
        const float4 v = ((const float4*)W_in)[e4];
        const int e = 4 * e4;
        Wt[(e + 0) % NQ][(e + 0) / NQ] = v.x;
        Wt[(e + 1) % NQ][(e + 1) / NQ] = v.y;
        Wt[(e + 2) % NQ][(e + 2) / NQ] = v.z;
        Wt[(e + 3) % NQ][(e + 3) / NQ] = v.w;
    }

    // ---- threads 0-9: Rot matrices + abc (hides under loads) ----
    if (t < NQ) {
        {
            float phi = qw[t * 3 + 0], th = qw[t * 3 + 1], om = qw[t * 3 + 2];
            float st_, ct;  sincosf(0.5f * th, &st_, &ct);
            float spo, cpo; sincosf(0.5f * (phi + om), &spo, &cpo);
            float spm, cpm; sincosf(0.5f * (phi - om), &spm, &cpm);
            Rsh[t][0] =  cpo * ct;  Rsh[t][1] = -spo * ct;
            Rsh[t][2] = -cpm * st_; Rsh[t][3] = -spm * st_;
            Rsh[t][4] =  cpm * st_; Rsh[t][5] = -spm * st_;
            Rsh[t][6] =  cpo * ct;  Rsh[t][7] =  spo * ct;
        }
        {
            float phi = qw[30 + t * 3 + 0], th = qw[30 + t * 3 + 1], om = qw[30 + t * 3 + 2];
            float st_, ct;  sincosf(0.5f * th, &st_, &ct);
            float spo, cpo; sincosf(0.5f * (phi + om), &spo, &cpo);
            float spm, cpm; sincosf(0.5f * (phi - om), &spm, &cpm);
            float2 G00 = make_float2(cpo * ct, -spo * ct);
            float2 G01 = make_float2(-cpm * st_, -spm * st_);
            float2 G10 = make_float2(cpm * st_, -spm * st_);
            float2 G11 = make_float2(cpo * ct, spo * ct);
            float re = G00.x * G01.x + G00.y * G01.y - (G10.x * G11.x + G10.y * G11.y);
            float im = G00.x * G01.y - G00.y * G01.x - (G10.x * G11.y - G10.y * G11.x);
            float A00 = G00.x * G00.x + G00.y * G00.y - (G10.x * G10.x + G10.y * G10.y);
            float A11 = G01.x * G01.x + G01.y * G01.y - (G11.x * G11.x + G11.y * G11.y);
            absh[t][0] = re;
            absh[t][1] = -im;
            absh[t][2] = 0.5f * (A00 - A11);
        }
    }
    __syncthreads();

    // ---- phase A: two row-GEMMs per wave from LDS ----
    {
        float a0[NQ], a1[NQ];
        #pragma unroll
        for (int q = 0; q < NQ; ++q) { a0[q] = 0.f; a1[q] = 0.f; }
        #pragma unroll
        for (int k = 0; k < 8; ++k) {
            const int j = lane + 64 * k;
            const float x0 = xv0[k], x1 = xv1[k];
            #pragma unroll
            for (int q = 0; q < NQ; ++q) {
                const float w = Wt[q][j];
                a0[q] = fmaf(x0, w, a0[q]);
                a1[q] = fmaf(x1, w, a1[q]);
            }
        }
        #pragma unroll
        for (int off = 32; off > 0; off >>= 1) {
            #pragma unroll
            for (int q = 0; q < NQ; ++q) {
                a0[q] += __shfl_xor(a0[q], off);
                a1[q] += __shfl_xor(a1[q], off);
            }
        }
        if (lane == 0) {
            #pragma unroll
            for (int q = 0; q < NQ; ++q) {
                angsh[wv][q]     = a0[q] + b_in[q];
                angsh[wv + 4][q] = a1[q] + b_in[q];
            }
        }
    }
    __syncthreads();

    // ---- phase B1: E2 pair tables (t<160, 8 rows) + A2 tables (160..179) ----
    if (t < 160) {
        const int rr = t / 20, rem = t % 20, p = rem >> 2, c1 = rem & 3;
        const int i0 = 2 * p, i1 = i0 + 1;
        float a0 = angsh[rr][i0];
        float a1 = angsh[rr][i1];
        float s0, c0f, s1, c1f;
        sincosf(0.5f * a0, &s0, &c0f);
        sincosf(0.5f * a1, &s1, &c1f);
        const float* Rp0 = Rsh[i0];
        const float* Rp1 = Rsh[i1];
        float2 u0 = make_float2(fmaf(Rp0[0], c0f, s0 * Rp0[3]), fmaf(Rp0[1], c0f, -s0 * Rp0[2]));
        float2 u1 = make_float2(fmaf(Rp0[4], c0f, s0 * Rp0[7]), fmaf(Rp0[5], c0f, -s0 * Rp0[6]));
        float ex0 = 2.f * (u0.x * u1.x + u0.y * u1.y);
        float ey0 = 2.f * (u0.x * u1.y - u0.y * u1.x);
        float ez0 = u0.x * u0.x + u0.y * u0.y - u1.x * u1.x - u1.y * u1.y;
        float2 v0 = make_float2(fmaf(Rp1[0], c1f, s1 * Rp1[3]), fmaf(Rp1[1], c1f, -s1 * Rp1[2]));
        float2 v1 = make_float2(fmaf(Rp1[4], c1f, s1 * Rp1[7]), fmaf(Rp1[5], c1f, -s1 * Rp1[6]));
        float ex1 = 2.f * (v0.x * v1.x + v0.y * v1.y);
        float ey1 = 2.f * (v0.x * v1.y - v0.y * v1.x);
        float ez1 = v0.x * v0.x + v0.y * v0.y - v1.x * v1.x - v1.y * v1.y;
        float e1 = (c1 == 0) ? 1.f : (c1 == 1) ? ex1 : (c1 == 2) ? ez1 : ey1;
        float e0arr[4] = {1.f, ex0, ez0, ey0};
        #pragma unroll
        for (int cc = 0; cc < 4; ++cc) {
            float v = e0arr[cc] * e1;
            int idx = cc | (c1 << 2);
            E2tmp[rr][p][idx] = v;
            if (p == 4) {
                E2P[rr][2 * idx]     = v;
                E2P[rr][2 * idx + 1] = v;
            }
        }
    } else if (t < 180) {
        const int rem = t - 160, p = rem >> 2, c1 = rem & 3;
        const int i0 = 2 * p, i1 = i0 + 1;
        float b1v = (c1 == 0) ? 1.f : (c1 == 1) ? absh[i1][0] : (c1 == 2) ? absh[i1][2] : absh[i1][1];
        float a0arr[4] = {1.f, absh[i0][0], absh[i0][2], absh[i0][1]};
        #pragma unroll
        for (int cc = 0; cc < 4; ++cc) {
            float v = a0arr[cc] * b1v;
            int idx = cc | (c1 << 2);
            A2tmp[p][idx] = v;
            if (p == 4) {
                A2P[2 * idx]     = v;
                A2P[2 * idx + 1] = v;
            }
        }
    }
    __syncthreads();

    // ---- phase B2: quad tables (E4: 16/thread, A4: 2/thread) ----
    #pragma unroll
    for (int k = 0; k < 16; ++k) {
        const int rr = k >> 1, qd = k & 1;
        E4d[rr][qd][t] = E2tmp[rr][2 * qd][t & 15] * E2tmp[rr][2 * qd + 1][t >> 4];
    }
    A4d[0][t] = A2tmp[0][t & 15] * A2tmp[1][t >> 4];
    A4d[1][t] = A2tmp[2][t & 15] * A2tmp[3][t >> 4];
    __syncthreads();

    // ---- phase C: contract terms against E4/E2P with A-table coefs ----
    float accR[RPB];
    #pragma unroll
    for (int rr = 0; rr < RPB; ++rr) accR[rr] = 0.f;
    {
        const int par = t & 1;
        #pragma unroll
        for (int s = 0; s < 8; ++s) {
            if (s < nsl) {
                const unsigned pre = tp[s].pre, post = tp[s].post;
                float cf = A4d[0][pre & 255] * A4d[1][(pre >> 8) & 255]
                         * A2P[2 * ((pre >> 16) & 15) + par];
                cf = (pre & (1u << 21)) ? cf : 0.f;
                cf = (pre & (1u << 20)) ? -cf : cf;
                const int i0 = post & 255, i1 = (post >> 8) & 255, ip = (post >> 16) & 15;
                #pragma unroll
                for (int rr = 0; rr < RPB; ++rr) {
                    float pr = cf * E4d[rr][0][i0];
                    pr *= E4d[rr][1][i1];
                    pr *= E2P[rr][2 * ip + par];
                    accR[rr] += pr;
                }
            }
        }
    }
    #pragma unroll
    for (int rr = 0; rr < RPB; ++rr) {
        accR[rr] += __shfl_xor(accR[rr], 1);
        accR[rr] += __shfl_xor(accR[rr], 2);
        accR[rr] += __shfl_xor(accR[rr], 4);
    }
    if (t < 192) {
        #pragma unroll
        for (int rr = 0; rr < RPB; ++rr) {
            accR[rr] += __shfl_xor(accR[rr], 8);
            accR[rr] += __shfl_xor(accR[rr], 16);
        }
    }
    {
        int qx = -1;
        if      (t == 0)   qx = 8;
        else if (t == 32)  qx = 9;
        else if (t == 64)  qx = 0;
        else if (t == 96)  qx = 1;
        else if (t == 128) qx = 6;
        else if (t == 160) qx = 7;
        else if (t == 192) qx = 4;
        else if (t == 200) qx = 5;
        else if (t == 208) qx = 2;
        else if (t == 216) qx = 3;
        if (qx >= 0) {
            #pragma unroll
            for (int rr = 0; rr < RPB; ++rr) zsh[rr][qx] = accR[rr];
        }
    }
    __syncthreads();

    // ---- phase D: h = relu(z @ W1 + b1); 8 rows x 64 cols, 2 jobs/thread ----
    #pragma unroll
    for (int rep = 0; rep < 2; ++rep) {
        const int job = t + rep * 256;
        const int rr = job >> 6, c = job & 63;
        float a = b1[c];
        #pragma unroll
        for (int i = 0; i < NQ; ++i) a = fmaf(zsh[rr][i], W1[i * 64 + c], a);
        hsh[rr][c] = fmaxf(a, 0.f);
    }
    __syncthreads();

    // ---- phase E: out = tanh(h @ W2 + b2), thread owns column t, 8 rows ----
    {
        float oacc[RPB];
        const float bb = b2[t];
        #pragma unroll
        for (int rr = 0; rr < RPB; ++rr) oacc[rr] = bb;
        for (int j4 = 0; j4 < 16; ++j4) {
            const float w0 = W2[(4 * j4 + 0) * 256 + t];
            const float w1 = W2[(4 * j4 + 1) * 256 + t];
            const float w2 = W2[(4 * j4 + 2) * 256 + t];
            const float w3 = W2[(4 * j4 + 3) * 256 + t];
            #pragma unroll
            for (int rr = 0; rr < RPB; ++rr) {
                float4 hv = *(const float4*)&hsh[rr][4 * j4];
                oacc[rr] = fmaf(hv.x, w0, oacc[rr]);
                oacc[rr] = fmaf(hv.y, w1, oacc[rr]);
                oacc[rr] = fmaf(hv.z, w2, oacc[rr]);
                oacc[rr] = fmaf(hv.w, w3, oacc[rr]);
            }
        }
        #pragma unroll
        for (int rr = 0; rr < RPB; ++rr)
            out[(size_t)(row0 + rr) * 256 + t] = fast_tanh(oacc[rr]);
    }
}

extern "C" void kernel_launch(void* const* d_in, const int* in_sizes, int n_in,
                              void* d_out, int out_size, void* d_ws, size_t ws_size,
                              hipStream_t stream) {
    const float* x    = (const float*)d_in[0];
    const float* W_in = (const float*)d_in[1];
    const float* b_in = (const float*)d_in[2];
    const float* qw   = (const float*)d_in[3];
    const float* W1   = (const float*)d_in[4];
    const float* b1   = (const float*)d_in[5];
    const float* W2   = (const float*)d_in[6];
    const float* b2   = (const float*)d_in[7];
    float* out = (float*)d_out;

    qse_mega<<<512, 256, 0, stream>>>(x, W_in, b_in, qw, W1, b1, W2, b2, out);
}

// Round 13
// 84.368 us; speedup vs baseline: 1.0126x; 1.0126x over previous
//
#include <hip/hip_runtime.h>
#include <math.h>

#define NQ 10

// ---------------------------------------------------------------------------
// Compile-time term table. Slot u = s*256 + lane. Variable slots per wave:
//   wave0 (lanes 0-63): 8   wave1: 3   wave2: 3   wave3: 4
// Lane groups (pow2-aligned for shfl_xor segment reduce):
//   0-31:q8  32-63:q9  64-95:q0  96-127:q1  128-159:q6  160-191:q7
//   192-199:q4  200-207:q5  208-215:q2  216-223:q3  224-255: invalid
// post: packed POST-ring1-conj site codes (x|z<<1), bits 0-19.
// pre : packed PRE-conj codes (bits 0-19) | sign<<20 | valid<<21.
// Term = sign * [prod a(i,pre_i)] * [prod E(i,post_i)], quad-factored:
// idx0 = w&255 (sites0-3), idx1 = (w>>8)&255 (sites4-7), idxp = (w>>16)&15.
// ---------------------------------------------------------------------------
struct TP { unsigned post, pre; };
struct TermsTab { TP t[2048]; };

constexpr TermsTab build_terms() {
    TermsTab T{};
    for (int u = 0; u < 2048; ++u) {
        const int lane = u & 255, s = u >> 8;
        const int wvv = lane >> 6;
        const int nsl = (wvv == 0) ? 8 : ((wvv == 3) ? 4 : 3);
        int q = -1, g0 = 0;
        if      (lane < 32)  { q = 8; g0 = 0;   }
        else if (lane < 64)  { q = 9; g0 = 32;  }
        else if (lane < 96)  { q = 0; g0 = 64;  }
        else if (lane < 128) { q = 1; g0 = 96;  }
        else if (lane < 160) { q = 6; g0 = 128; }
        else if (lane < 192) { q = 7; g0 = 160; }
        else if (lane < 200) { q = 4; g0 = 192; }
        else if (lane < 208) { q = 5; g0 = 200; }
        else if (lane < 216) { q = 2; g0 = 208; }
        else if (lane < 224) { q = 3; g0 = 216; }
        T.t[u].post = 0u; T.t[u].pre = 0u;            // invalid default
        if (q < 0 || s >= nsl) continue;
        const int tau = (lane - g0) * nsl + s;

        int m = 1 << q;                               // ring-2 Z-string
        for (int ii = 9; ii >= 0; --ii) {
            int tt = (ii + 2) % 10;
            if ((m >> tt) & 1) m ^= 1 << ii;
        }
        int Lp = 0;
        for (int i = 0; i < 10; ++i) Lp += (m >> i) & 1;
        int cnt = 1;
        for (int k = 0; k < Lp; ++k) cnt *= 3;
        if (tau >= cnt) continue;

        int rem = tau;                                // digits: 0->X,1->Y,2->Z
        unsigned xm = 0, zm = 0;
        for (int i = 0; i < 10; ++i) {
            if ((m >> i) & 1) {
                int d = rem % 3; rem /= 3;
                if (d == 0)      { xm |= 1u << i; }
                else if (d == 1) { xm |= 1u << i; zm |= 1u << i; }
                else             { zm |= 1u << i; }
            }
        }
        unsigned wpre = 0;                            // pre-conj pack
        for (int i = 0; i < 10; ++i)
            wpre |= (((xm >> i) & 1u) | (((zm >> i) & 1u) << 1)) << (2 * i);

        unsigned sgn = 0;                             // ring-1 conj (i=9 first)
        for (int i = 9; i >= 0; --i) {
            int c = i, tt = (i + 1) % 10;
            unsigned xc = (xm >> c) & 1u, zt = (zm >> tt) & 1u;
            unsigned xt = (xm >> tt) & 1u, zc = (zm >> c) & 1u;
            sgn ^= xc & zt & (xt ^ zc ^ 1u);
            xm ^= xc << tt;
            zm ^= zt << c;
        }
        unsigned wpost = 0;                           // post-conj pack
        for (int i = 0; i < 10; ++i)
            wpost |= (((xm >> i) & 1u) | (((zm >> i) & 1u) << 1)) << (2 * i);

        T.t[u].post = wpost;
        T.t[u].pre  = wpre | (sgn << 20) | (1u << 21);
    }
    return T;
}

__device__ constexpr TermsTab TERMS = build_terms();

__device__ __forceinline__ float fast_tanh(float v) {
    float e = __expf(2.f * v);
    return 1.f - 2.f / (e + 1.f);     // saturates correctly at +/-inf
}

// ---------------------------------------------------------------------------
// Single mega kernel: W_in LDS-transpose + angles -> Rot/abc -> E2/A2 ->
// E4/A4 -> term contraction -> MLP. 4 rows/block, 256 threads, 1024 blocks.
// (RPB=4 is the measured optimum: r12's RPB=8 regressed — halved grid
//  residency cost more than the halved per-block fixed traffic saved.)
// ---------------------------------------------------------------------------
__global__ __launch_bounds__(256) void qse_mega(
    const float* __restrict__ x,     // (4096,512)
    const float* __restrict__ W_in,  // (512,10)
    const float* __restrict__ b_in,  // (10)
    const float* __restrict__ qw,    // (2,10,3)
    const float* __restrict__ W1,    // (10,64)
    const float* __restrict__ b1,    // (64)
    const float* __restrict__ W2,    // (64,256)
    const float* __restrict__ b2,    // (256)
    float* __restrict__ out)         // (4096,256)
{
    __shared__ float Wt[NQ][512];        // transposed W_in (20 KB)
    __shared__ float Rsh[NQ][8];         // layer-0 Rot matrices
    __shared__ float absh[NQ][3];        // layer-1 A = G†ZG Bloch coefs
    __shared__ float angsh[4][NQ];
    __shared__ float E2tmp[4][5][16];    // per-pair Bloch products
    __shared__ float E4d[4][2][256];     // quad products (sites 0-3, 4-7)
    __shared__ float E2P[4][32];         // pair (sites 8-9), duplicated x2
    __shared__ float A2tmp[5][16];       // per-pair abc products
    __shared__ float A4d[2][256];        // abc quad tables
    __shared__ float A2P[32];            // abc pair (sites 8-9), dup x2
    __shared__ float zsh[4][NQ];
    __shared__ float hsh[4][64];

    const int t = threadIdx.x;
    const int lane = t & 63;
    const int wv = t >> 6;
    const int row0 = blockIdx.x * 4;
    const int nsl = (wv == 0) ? 8 : ((wv == 3) ? 4 : 3);

    // ---- issue x loads (8 coalesced dwords per thread, wave wv = row wv) ----
    const float* xr = x + (size_t)(row0 + wv) * 512;
    float xv[8];
    #pragma unroll
    for (int k = 0; k < 8; ++k) xv[k] = xr[lane + 64 * k];

    // ---- prefetch term codes (constexpr table in .rodata/L2) ----
    TP tp[8];
    #pragma unroll
    for (int s = 0; s < 8; ++s)
        tp[s] = (s < nsl) ? TERMS.t[s * 256 + t] : TP{0u, 0u};

    // ---- stage W_in transposed into LDS (coalesced float4 reads) ----
    #pragma unroll
    for (int i = 0; i < 5; ++i) {
        const int e4 = t + 256 * i;
        const float4 v = ((const float4*)W_in)[e4];
        const int e = 4 * e4;
        Wt[(e + 0) % NQ][(e + 0) / NQ] = v.x;
        Wt[(e + 1) % NQ][(e + 1) / NQ] = v.y;
        Wt[(e + 2) % NQ][(e + 2) / NQ] = v.z;
        Wt[(e + 3) % NQ][(e + 3) / NQ] = v.w;
    }

    // ---- threads 0-9: per-block Rot matrices + abc (hides under loads) ----
    if (t < NQ) {
        {   // layer-0 Rot
            float phi = qw[t * 3 + 0], th = qw[t * 3 + 1], om = qw[t * 3 + 2];
            float st_, ct;  sincosf(0.5f * th, &st_, &ct);
            float spo, cpo; sincosf(0.5f * (phi + om), &spo, &cpo);
            float spm, cpm; sincosf(0.5f * (phi - om), &spm, &cpm);
            Rsh[t][0] =  cpo * ct;  Rsh[t][1] = -spo * ct;
            Rsh[t][2] = -cpm * st_; Rsh[t][3] = -spm * st_;
            Rsh[t][4] =  cpm * st_; Rsh[t][5] = -spm * st_;
            Rsh[t][6] =  cpo * ct;  Rsh[t][7] =  spo * ct;
        }
        {   // layer-1: A = G† Z G Bloch coefficients
            float phi = qw[30 + t * 3 + 0], th = qw[30 + t * 3 + 1], om = qw[30 + t * 3 + 2];
            float st_, ct;  sincosf(0.5f * th, &st_, &ct);
            float spo, cpo; sincosf(0.5f * (phi + om), &spo, &cpo);
            float spm, cpm; sincosf(0.5f * (phi - om), &spm, &cpm);
            float2 G00 = make_float2(cpo * ct, -spo * ct);
            float2 G01 = make_float2(-cpm * st_, -spm * st_);
            float2 G10 = make_float2(cpm * st_, -spm * st_);
            float2 G11 = make_float2(cpo * ct, spo * ct);
            float re = G00.x * G01.x + G00.y * G01.y - (G10.x * G11.x + G10.y * G11.y);
            float im = G00.x * G01.y - G00.y * G01.x - (G10.x * G11.y - G10.y * G11.x);
            float A00 = G00.x * G00.x + G00.y * G00.y - (G10.x * G10.x + G10.y * G10.y);
            float A11 = G01.x * G01.x + G01.y * G01.y - (G11.x * G11.x + G11.y * G11.y);
            absh[t][0] = re;
            absh[t][1] = -im;
            absh[t][2] = 0.5f * (A00 - A11);
        }
    }
    __syncthreads();

    // ---- phase A: angles GEMM from LDS (conflict-free stride-1 reads) ----
    {
        float acc[NQ];
        #pragma unroll
        for (int q = 0; q < NQ; ++q) acc[q] = 0.f;
        #pragma unroll
        for (int k = 0; k < 8; ++k) {
            const int j = lane + 64 * k;
            const float xj = xv[k];
            #pragma unroll
            for (int q = 0; q < NQ; ++q) acc[q] = fmaf(xj, Wt[q][j], acc[q]);
        }
        #pragma unroll
        for (int off = 32; off > 0; off >>= 1) {
            #pragma unroll
            for (int q = 0; q < NQ; ++q) acc[q] += __shfl_xor(acc[q], off);
        }
        if (lane == 0) {
            #pragma unroll
            for (int q = 0; q < NQ; ++q) angsh[wv][q] = acc[q] + b_in[q];
        }
    }
    __syncthreads();

    // ---- phase B1: E2 pair tables (t<80) + A2 abc tables (t in 80..99) ----
    if (t < 80) {
        const int rr = t / 20, rem = t % 20, p = rem >> 2, c1 = rem & 3;
        const int i0 = 2 * p, i1 = i0 + 1;
        float a0 = angsh[rr][i0];
        float a1 = angsh[rr][i1];
        float s0, c0f, s1, c1f;
        sincosf(0.5f * a0, &s0, &c0f);
        sincosf(0.5f * a1, &s1, &c1f);
        const float* Rp0 = Rsh[i0];
        const float* Rp1 = Rsh[i1];
        float2 u0 = make_float2(fmaf(Rp0[0], c0f, s0 * Rp0[3]), fmaf(Rp0[1], c0f, -s0 * Rp0[2]));
        float2 u1 = make_float2(fmaf(Rp0[4], c0f, s0 * Rp0[7]), fmaf(Rp0[5], c0f, -s0 * Rp0[6]));
        float ex0 = 2.f * (u0.x * u1.x + u0.y * u1.y);
        float ey0 = 2.f * (u0.x * u1.y - u0.y * u1.x);
        float ez0 = u0.x * u0.x + u0.y * u0.y - u1.x * u1.x - u1.y * u1.y;
        float2 v0 = make_float2(fmaf(Rp1[0], c1f, s1 * Rp1[3]), fmaf(Rp1[1], c1f, -s1 * Rp1[2]));
        float2 v1 = make_float2(fmaf(Rp1[4], c1f, s1 * Rp1[7]), fmaf(Rp1[5], c1f, -s1 * Rp1[6]));
        float ex1 = 2.f * (v0.x * v1.x + v0.y * v1.y);
        float ey1 = 2.f * (v0.x * v1.y - v0.y * v1.x);
        float ez1 = v0.x * v0.x + v0.y * v0.y - v1.x * v1.x - v1.y * v1.y;
        float e1 = (c1 == 0) ? 1.f : (c1 == 1) ? ex1 : (c1 == 2) ? ez1 : ey1;
        float e0arr[4] = {1.f, ex0, ez0, ey0};
        #pragma unroll
        for (int cc = 0; cc < 4; ++cc) {
            float v = e0arr[cc] * e1;
            int idx = cc | (c1 << 2);
            E2tmp[rr][p][idx] = v;
            if (p == 4) {
                E2P[rr][2 * idx]     = v;
                E2P[rr][2 * idx + 1] = v;
            }
        }
    } else if (t < 100) {
        const int rem = t - 80, p = rem >> 2, c1 = rem & 3;
        const int i0 = 2 * p, i1 = i0 + 1;
        // a(i, code): code0 -> 1, code1 -> X=absh[i][0], code2 -> Z=absh[i][2], code3 -> Y=absh[i][1]
        float b1v = (c1 == 0) ? 1.f : (c1 == 1) ? absh[i1][0] : (c1 == 2) ? absh[i1][2] : absh[i1][1];
        float a0arr[4] = {1.f, absh[i0][0], absh[i0][2], absh[i0][1]};
        #pragma unroll
        for (int cc = 0; cc < 4; ++cc) {
            float v = a0arr[cc] * b1v;
            int idx = cc | (c1 << 2);
            A2tmp[p][idx] = v;
            if (p == 4) {
                A2P[2 * idx]     = v;
                A2P[2 * idx + 1] = v;
            }
        }
    }
    __syncthreads();

    // ---- phase B2: quad tables (E4: 8/thread, A4: 2/thread) ----
    #pragma unroll
    for (int k = 0; k < 8; ++k) {
        const int rr = k >> 1, qd = k & 1;
        E4d[rr][qd][t] = E2tmp[rr][2 * qd][t & 15] * E2tmp[rr][2 * qd + 1][t >> 4];
    }
    A4d[0][t] = A2tmp[0][t & 15] * A2tmp[1][t >> 4];
    A4d[1][t] = A2tmp[2][t & 15] * A2tmp[3][t >> 4];
    __syncthreads();

    // ---- phase C: contract terms against E4/E2P with A-table coefs ----
    float accR[4] = {0.f, 0.f, 0.f, 0.f};
    {
        const int par = t & 1;
        #pragma unroll
        for (int s = 0; s < 8; ++s) {
            if (s < nsl) {
                const unsigned pre = tp[s].pre, post = tp[s].post;
                float cf = A4d[0][pre & 255] * A4d[1][(pre >> 8) & 255]
                         * A2P[2 * ((pre >> 16) & 15) + par];
                cf = (pre & (1u << 21)) ? cf : 0.f;
                cf = (pre & (1u << 20)) ? -cf : cf;
                const int i0 = post & 255, i1 = (post >> 8) & 255, ip = (post >> 16) & 15;
                #pragma unroll
                for (int rr = 0; rr < 4; ++rr) {
                    float pr = cf * E4d[rr][0][i0];
                    pr *= E4d[rr][1][i1];
                    pr *= E2P[rr][2 * ip + par];
                    accR[rr] += pr;
                }
            }
        }
    }
    #pragma unroll
    for (int rr = 0; rr < 4; ++rr) {
        accR[rr] += __shfl_xor(accR[rr], 1);
        accR[rr] += __shfl_xor(accR[rr], 2);
        accR[rr] += __shfl_xor(accR[rr], 4);
    }
    if (t < 192) {
        #pragma unroll
        for (int rr = 0; rr < 4; ++rr) {
            accR[rr] += __shfl_xor(accR[rr], 8);
            accR[rr] += __shfl_xor(accR[rr], 16);
        }
    }
    {
        int qx = -1;
        if      (t == 0)   qx = 8;
        else if (t == 32)  qx = 9;
        else if (t == 64)  qx = 0;
        else if (t == 96)  qx = 1;
        else if (t == 128) qx = 6;
        else if (t == 160) qx = 7;
        else if (t == 192) qx = 4;
        else if (t == 200) qx = 5;
        else if (t == 208) qx = 2;
        else if (t == 216) qx = 3;
        if (qx >= 0) {
            #pragma unroll
            for (int rr = 0; rr < 4; ++rr) zsh[rr][qx] = accR[rr];
        }
    }
    __syncthreads();

    // ---- phase D: h = relu(z @ W1 + b1); 4 rows x 64 cols ----
    {
        const int rr = t >> 6, c = t & 63;
        float a = b1[c];
        #pragma unroll
        for (int i = 0; i < NQ; ++i) a = fmaf(zsh[rr][i], W1[i * 64 + c], a);
        hsh[rr][c] = fmaxf(a, 0.f);
    }
    __syncthreads();

    // ---- phase E: out = tanh(h @ W2 + b2), thread owns column t, 4 rows ----
    {
        float oacc[4];
        const float bb = b2[t];
        #pragma unroll
        for (int rr = 0; rr < 4; ++rr) oacc[rr] = bb;
        for (int j4 = 0; j4 < 16; ++j4) {
            const float w0 = W2[(4 * j4 + 0) * 256 + t];
            const float w1 = W2[(4 * j4 + 1) * 256 + t];
            const float w2 = W2[(4 * j4 + 2) * 256 + t];
            const float w3 = W2[(4 * j4 + 3) * 256 + t];
            #pragma unroll
            for (int rr = 0; rr < 4; ++rr) {
                float4 hv = *(const float4*)&hsh[rr][4 * j4];
                oacc[rr] = fmaf(hv.x, w0, oacc[rr]);
                oacc[rr] = fmaf(hv.y, w1, oacc[rr]);
                oacc[rr] = fmaf(hv.z, w2, oacc[rr]);
                oacc[rr] = fmaf(hv.w, w3, oacc[rr]);
            }
        }
        #pragma unroll
        for (int rr = 0; rr < 4; ++rr)
            out[(size_t)(row0 + rr) * 256 + t] = fast_tanh(oacc[rr]);
    }
}

extern "C" void kernel_launch(void* const* d_in, const int* in_sizes, int n_in,
                              void* d_out, int out_size, void* d_ws, size_t ws_size,
                              hipStream_t stream) {
    const float* x    = (const float*)d_in[0];
    const float* W_in = (const float*)d_in[1];
    const float* b_in = (const float*)d_in[2];
    const float* qw   = (const float*)d_in[3];
    const float* W1   = (const float*)d_in[4];
    const float* b1   = (const float*)d_in[5];
    const float* W2   = (const float*)d_in[6];
    const float* b2   = (const float*)d_in[7];
    float* out = (float*)d_out;

    qse_mega<<<1024, 256, 0, stream>>>(x, W_in, b_in, qw, W1, b1, W2, b2, out);
}